// Round 2
// baseline (198.738 us; speedup 1.0000x reference)
//
#include <hip/hip_runtime.h>
#include <math.h>

// Fused copy + n-gram ban, one dispatch — round 2.
//
// Round-1 failure mode: copy phase ran at 2.4 TB/s (67 us) because the
// stride-256 runtime-bound loop kept ~1 float4 in flight per wave while
// block residency dropped to ~5/CU. Fix: 4-deep hand-unrolled copy
// (4 independent loads then 4 stores = 4 KB in flight per wave), bigger
// chunks (fewer blocks, less redundant window scanning), 32-bit divides.
//
// Chunk = 3072 float4s = 12288 floats < V(50257) => a chunk overlaps at
// most 2 rows. Full blocks do exactly 12 float4s/thread = 3 unrolled iters.
// Ban writes only touch addresses this block copied, so one block-local
// __syncthreads() orders copy-before-ban. Tail (total_f % 4) is copied by
// the LAST block, which also scans the last row => tail ordering is safe.
//
// Worst-case bans/chunk = 2 rows * num_windows(1019) = 2038 <= 2048.

#define CHUNK4   3072
#define MAX_BANS 2048

__global__ void __launch_bounds__(256)
ngram_fused(const float4* __restrict__ in4, float4* __restrict__ out4,
            const float* __restrict__ in, float* __restrict__ out,
            const int* __restrict__ tokens,
            const int* __restrict__ bsz_p, const int* __restrict__ step_p,
            const int* __restrict__ beam_p, const int* __restrict__ n_p,
            int tok_elems, int total_f, int n4) {
    __shared__ int s_cnt;
    __shared__ int s_ban[MAX_BANS];

    const int b   = blockIdx.x;
    const int t   = threadIdx.x;
    const int lo4 = b * CHUNK4;
    const int hi4 = (lo4 + CHUNK4 < n4) ? lo4 + CHUNK4 : n4;

    if (t == 0) s_cnt = 0;
    __syncthreads();   // s_cnt visible before any atomicAdd in phase 2

    // ---- phase 1: copy, 4 independent float4s in flight per wave ----
    {
        int i = lo4 + t;
        while (i + 768 < hi4) {
            float4 v0 = in4[i];
            float4 v1 = in4[i + 256];
            float4 v2 = in4[i + 512];
            float4 v3 = in4[i + 768];
            out4[i]       = v0;
            out4[i + 256] = v1;
            out4[i + 512] = v2;
            out4[i + 768] = v3;
            i += 1024;
        }
        for (; i < hi4; i += 256) out4[i] = in4[i];
    }
    // tail (total_f % 4): copied by the LAST block (it also scans the
    // last row, so its barrier orders these stores before ban writes).
    if (b == gridDim.x - 1) {
        int tf = n4 * 4 + t;
        if (tf < total_f) out[tf] = in[tf];
    }

    // ---- phase 2: window scan for the (<=2) rows overlapping this chunk ----
    const int bsz  = *bsz_p;
    const int step = *step_p;
    const int beam = *beam_p;
    const int n    = *n_p;

    const int R = bsz * beam;
    const int S = tok_elems / R;          // 32-bit div (tok_elems fits int)
    const int V = total_f / R;
    const int num_windows = step - n + 2;
    const int last_start  = step - n + 2;
    const int L = n - 1;

    const int flo = lo4 * 4;
    const int fhi = (b == gridDim.x - 1) ? total_f : hi4 * 4;

    const int r0 = flo / V;
    const int r1 = (fhi - 1) / V;

    for (int r = r0; r <= r1; ++r) {
        const int* __restrict__ trow = tokens + (long long)r * S;
        const int rebase = r * V - flo;   // row base relative to chunk start
        for (int j = t; j < num_windows; j += 256) {
            bool m = true;
            for (int k = 0; k < L; ++k) {
                m &= (trow[j + k] == trow[last_start + k]);
            }
            if (m) {
                const int f = rebase + trow[j + n - 1];
                if (f >= 0 && f < fhi - flo) {
                    int idx = atomicAdd(&s_cnt, 1);
                    if (idx < MAX_BANS) s_ban[idx] = f;
                }
            }
        }
    }

    // ---- phase 3: ordered ban writes ----
    __syncthreads();
    const int cnt = (s_cnt < MAX_BANS) ? s_cnt : MAX_BANS;
    for (int i = t; i < cnt; i += 256) {
        out[flo + s_ban[i]] = -INFINITY;
    }
}

extern "C" void kernel_launch(void* const* d_in, const int* in_sizes, int n_in,
                              void* d_out, int out_size, void* d_ws, size_t ws_size,
                              hipStream_t stream) {
    const int*   tokens = (const int*)d_in[0];
    const float* lprobs = (const float*)d_in[1];
    const int*   bsz_p  = (const int*)d_in[2];
    const int*   step_p = (const int*)d_in[3];
    const int*   beam_p = (const int*)d_in[4];
    const int*   n_p    = (const int*)d_in[5];
    float* out = (float*)d_out;

    const int total_f = out_size;                    // 25,731,584 elements
    const int n4      = total_f / 4;                 // 6,432,896
    const int blocks  = (n4 + CHUNK4 - 1) / CHUNK4;  // 2095

    ngram_fused<<<blocks, 256, 0, stream>>>(
        (const float4*)lprobs, (float4*)out, lprobs, out,
        tokens, bsz_p, step_p, beam_p, n_p,
        (int)in_sizes[0], total_f, n4);
}

// Round 3
// 195.255 us; speedup vs baseline: 1.0178x; 1.0178x over previous
//
#include <hip/hip_runtime.h>
#include <math.h>

// Round 3: back to two stream-ordered stages (fusion measured 2× slower on
// the copy phase in rounds 1-2: block lifetime = copy+barrier+scan+scatter
// throttled fresh-load supply to ~3 TB/s effective).
//
// Stage 1: runtime D2D copy (hipMemcpyAsync — graph-capture-safe per G9).
//          The runtime blit/SDMA path is the measured gold standard
//          (~85% of achievable BW, same class as the 6.9 TB/s fill kernel
//          seen in the profile), vs our best kernel copy estimate ~3 TB/s.
// Stage 2: tiny ban scan + scatter, stream-ordered after the copy.
//          One block per row; "last" (n-1)-gram cached in registers.

__global__ void __launch_bounds__(256)
ngram_ban(const int* __restrict__ tokens, float* __restrict__ out,
          const int* __restrict__ bsz_p, const int* __restrict__ step_p,
          const int* __restrict__ beam_p, const int* __restrict__ n_p,
          long long tok_elems, long long lp_elems) {
    const int bsz  = *bsz_p;
    const int step = *step_p;
    const int beam = *beam_p;
    const int n    = *n_p;

    const int R = bsz * beam;
    const long long S = tok_elems / R;
    const long long V = lp_elems / R;
    const int num_windows = step - n + 2;
    const int last_start  = step - n + 2;
    const int L = n - 1;   // 2 for this shape, but keep general

    for (int r = blockIdx.x; r < R; r += gridDim.x) {
        const int* __restrict__ trow = tokens + (long long)r * S;

        // cache the suffix (n-1 tokens, L<=7 supported here) in registers
        int last[7];
        #pragma unroll
        for (int k = 0; k < 7; ++k)
            last[k] = (k < L) ? trow[last_start + k] : 0;

        for (int j = threadIdx.x; j < num_windows; j += blockDim.x) {
            bool m = true;
            for (int k = 0; k < L; ++k) {
                m &= (trow[j + k] == last[k]);
            }
            if (m) {
                const int banned = trow[j + n - 1];
                out[(long long)r * V + banned] = -INFINITY;
            }
        }
    }
}

extern "C" void kernel_launch(void* const* d_in, const int* in_sizes, int n_in,
                              void* d_out, int out_size, void* d_ws, size_t ws_size,
                              hipStream_t stream) {
    const int*   tokens = (const int*)d_in[0];
    const float* lprobs = (const float*)d_in[1];
    const int*   bsz_p  = (const int*)d_in[2];
    const int*   step_p = (const int*)d_in[3];
    const int*   beam_p = (const int*)d_in[4];
    const int*   n_p    = (const int*)d_in[5];
    float* out = (float*)d_out;

    // 1) bulk copy via the runtime's D2D path (blit/SDMA — graph-capturable)
    hipMemcpyAsync(out, lprobs, (size_t)out_size * sizeof(float),
                   hipMemcpyDeviceToDevice, stream);

    // 2) tiny ban scan + scatter (stream-ordered after the copy)
    ngram_ban<<<512, 256, 0, stream>>>(
        tokens, out, bsz_p, step_p, beam_p, n_p,
        (long long)in_sizes[0], (long long)in_sizes[1]);
}

// Round 4
// 190.856 us; speedup vs baseline: 1.0413x; 1.0231x over previous
//
#include <hip/hip_runtime.h>
#include <math.h>

// Round 4: restore the best-measured structure (round 0, 191.5 us) —
// two stream-ordered dispatches. Evidence from rounds 1-3:
//   - fused single-dispatch: copy phase capped at 2.4 TB/s (67 us) — worse
//   - runtime blit (hipMemcpyAsync): 195.3 us total — no better
//   - all copy variants land in the same ~60-67 us band; FETCH shows ~half
//     the reads are L3 hits yet rate stays ~3 TB/s => context-capped
//     (timed region shares HBM with the harness's 411 MB poison fills),
//     not BW/MLP-bound. Keep the simplest proven copy.
//
// Kernel 1: m13-style pure copy — one float4 per thread, 256-thread blocks,
// exact grid, 32-bit indexing. Tail handled by block 0.
__global__ void __launch_bounds__(256)
ngram_copy(const float4* __restrict__ in4, float4* __restrict__ out4,
           const float* __restrict__ in, float* __restrict__ out,
           int n4, int tail) {
    int i = blockIdx.x * 256 + threadIdx.x;
    if (i < n4) out4[i] = in4[i];
    if (blockIdx.x == 0 && threadIdx.x < tail) {
        int t = n4 * 4 + threadIdx.x;
        out[t] = in[t];
    }
}

// Kernel 2: ban scan + scatter. One block per row (grid-stride for safety);
// 1024 threads so the ~1019 windows are covered in one pass. The (n-1)-token
// suffix is cached in registers, hoisted out of the window loop.
__global__ void __launch_bounds__(1024)
ngram_ban(const int* __restrict__ tokens, float* __restrict__ out,
          const int* __restrict__ bsz_p, const int* __restrict__ step_p,
          const int* __restrict__ beam_p, const int* __restrict__ n_p,
          long long tok_elems, long long lp_elems) {
    const int bsz  = *bsz_p;
    const int step = *step_p;
    const int beam = *beam_p;
    const int n    = *n_p;

    const int R = bsz * beam;
    const long long S = tok_elems / R;
    const long long V = lp_elems / R;
    const int num_windows = step - n + 2;
    const int last_start  = step - n + 2;
    const int L = n - 1;   // 2 for this shape; supports up to 7

    for (int r = blockIdx.x; r < R; r += gridDim.x) {
        const int* __restrict__ trow = tokens + (long long)r * S;

        int last[7];
        #pragma unroll
        for (int k = 0; k < 7; ++k)
            last[k] = (k < L) ? trow[last_start + k] : 0;

        for (int j = threadIdx.x; j < num_windows; j += blockDim.x) {
            bool m = true;
            for (int k = 0; k < L; ++k) {
                m &= (trow[j + k] == last[k]);
            }
            if (m) {
                const int banned = trow[j + n - 1];
                out[(long long)r * V + banned] = -INFINITY;
            }
        }
    }
}

extern "C" void kernel_launch(void* const* d_in, const int* in_sizes, int n_in,
                              void* d_out, int out_size, void* d_ws, size_t ws_size,
                              hipStream_t stream) {
    const int*   tokens = (const int*)d_in[0];
    const float* lprobs = (const float*)d_in[1];
    const int*   bsz_p  = (const int*)d_in[2];
    const int*   step_p = (const int*)d_in[3];
    const int*   beam_p = (const int*)d_in[4];
    const int*   n_p    = (const int*)d_in[5];
    float* out = (float*)d_out;

    // 1) pure copy: exact grid, one float4/thread (best-measured variant)
    {
        const int n4   = out_size / 4;        // 6,432,896 for this shape
        const int tail = out_size - n4 * 4;   // 0 here
        const int blocks = (n4 + 255) / 256;
        ngram_copy<<<blocks, 256, 0, stream>>>(
            (const float4*)lprobs, (float4*)out, lprobs, out, n4, tail);
    }

    // 2) tiny ban scan + scatter (stream-ordered after the copy)
    {
        ngram_ban<<<512, 1024, 0, stream>>>(
            tokens, out, bsz_p, step_p, beam_p, n_p,
            (long long)in_sizes[0], (long long)in_sizes[1]);
    }
}